// Round 2
// baseline (499.472 us; speedup 1.0000x reference)
//
#include <hip/hip_runtime.h>
#include <hip/hip_bf16.h>
#include <math.h>

// attr = labels(1024x50000 f32) @ weight(50000x300 f32); out = attr/(||attr||+1e-7)
// k1: weight -> Wt[n][k] bf16 (n padded to 320) -- LDS transpose
// k2: split-K MFMA GEMM, NO-LDS: fragments read directly from global.
//     A (f32) converted to bf16 in-register; A reuse via L1, Wt via L2/L3.
//     No barriers -> waves free-run; latency hidden by TLP + A prefetch.
// k3: reduce partials over splits + row L2 normalize (fused)
typedef __bf16 bf16;
typedef bf16 bf16x8 __attribute__((ext_vector_type(8)));
typedef float f32x4 __attribute__((ext_vector_type(4)));

constexpr int Mdim = 1024;
constexpr int Kdim = 50000;
constexpr int Ndim = 300;
constexpr int NP   = 320;

constexpr int BM = 64, BN = 320;
constexpr int MT = Mdim / BM;      // 16 m-tiles

__device__ __forceinline__ bf16x8 bzero8() {
    bf16x8 v;
#pragma unroll
    for (int e = 0; e < 8; ++e) v[e] = (bf16)0.0f;
    return v;
}
__device__ __forceinline__ f32x4 fzero4() {
    f32x4 v;
#pragma unroll
    for (int e = 0; e < 4; ++e) v[e] = 0.0f;
    return v;
}

// ---------------- k1: transpose + convert -----------------------------------
constexpr int TK = 64;
constexpr int TS = 301;
__global__ __launch_bounds__(256) void transpose_w(const float* __restrict__ W,
                                                   bf16* __restrict__ Wt)
{
    __shared__ bf16 tile[TK * TS];
    const int k0 = blockIdx.x * TK;
    const int t  = threadIdx.x;

    for (int c = t; c < 64 * 75; c += 256) {
        const int kk = c / 75;
        const int ch = c % 75;
        const int k  = k0 + kk;
        float4 v = make_float4(0.f, 0.f, 0.f, 0.f);
        if (k < Kdim) v = *(const float4*)(W + (size_t)k * Ndim + ch * 4);
        bf16* p = &tile[kk * TS + ch * 4];
        p[0] = (bf16)v.x; p[1] = (bf16)v.y; p[2] = (bf16)v.z; p[3] = (bf16)v.w;
    }
    __syncthreads();
    for (int c = t; c < NP * 8; c += 256) {
        const int n  = c >> 3;
        const int ch = c & 7;
        const int k  = k0 + ch * 8;
        if (k + 8 <= Kdim) {
            bf16x8 v = bzero8();
            if (n < Ndim) {
#pragma unroll
                for (int j = 0; j < 8; ++j) v[j] = tile[(ch * 8 + j) * TS + n];
            }
            *(bf16x8*)(Wt + (size_t)n * Kdim + k) = v;
        }
    }
}

// ---------------- k2: no-LDS split-K MFMA GEMM ------------------------------
// ATOMIC=false: out = P, partials at P[ks][Mdim][NP] (plain stores)
// ATOMIC=true : out = Cacc[Mdim][NP] (atomicAdd), Cacc pre-zeroed
template<int SPLIT, int SEGLEN, bool ATOMIC>
__global__ __launch_bounds__(512, 4) void gemm_kernel(const float* __restrict__ A,
                                                      const bf16* __restrict__ Wt,
                                                      float* __restrict__ out)
{
    const int bx   = blockIdx.x;
    const int mt   = bx & (MT - 1);
    const int ks   = bx >> 4;
    const int m0   = mt * BM;
    const int kbeg = ks * SEGLEN;
    const int kend = min(kbeg + SEGLEN, Kdim);
    const int klen = kend - kbeg;

    const int t    = threadIdx.x;
    const int lane = t & 63;
    const int wave = t >> 6;         // 0..7 as 2m x 4n
    const int wm   = wave >> 2;
    const int wn   = wave & 3;
    const int lm   = lane & 15;
    const int lq   = lane >> 4;      // 0..3 -> k = lq*8

    // uniform 64-bit bases + 32-bit per-lane row offsets (saves VGPRs)
    const float* Ab = A  + (size_t)kbeg + lq * 8;
    const bf16*  Bb = Wt + (size_t)kbeg + lq * 8;
    unsigned aoff[2], boff[5];
#pragma unroll
    for (int i = 0; i < 2; ++i)
        aoff[i] = (unsigned)((m0 + wm * 32 + i * 16 + lm) * Kdim);
#pragma unroll
    for (int j = 0; j < 5; ++j)
        boff[j] = (unsigned)((wn * 80 + j * 16 + lm) * Kdim);

    const int lk = lq * 8;           // lane k offset within step

    f32x4  acc[2][5] = {};
    f32x4  a0[2][2], a1[2][2];       // A f32 stage, double-buffered
    bf16x8 b[5];

    auto loadA = [&](f32x4 dst[2][2], int koff) {
        if (lk + koff + 8 <= klen) {
#pragma unroll
            for (int i = 0; i < 2; ++i) {
                dst[i][0] = *(const f32x4*)(Ab + aoff[i] + koff);
                dst[i][1] = *(const f32x4*)(Ab + aoff[i] + koff + 4);
            }
        } else {
#pragma unroll
            for (int i = 0; i < 2; ++i) { dst[i][0] = fzero4(); dst[i][1] = fzero4(); }
        }
    };
    auto loadB = [&](int koff) {
        const bool ok = (lk + koff + 8 <= klen);
#pragma unroll
        for (int j = 0; j < 5; ++j)
            b[j] = ok ? *(const bf16x8*)(Bb + boff[j] + koff) : bzero8();
    };
    auto compute = [&](const f32x4 a[2][2]) {
        bf16x8 af[2];
#pragma unroll
        for (int i = 0; i < 2; ++i)
#pragma unroll
            for (int e = 0; e < 4; ++e) {
                af[i][e]     = (bf16)a[i][0][e];
                af[i][4 + e] = (bf16)a[i][1][e];
            }
#pragma unroll
        for (int i = 0; i < 2; ++i)
#pragma unroll
            for (int j = 0; j < 5; ++j)
                acc[i][j] = __builtin_amdgcn_mfma_f32_16x16x32_bf16(af[i], b[j], acc[i][j], 0, 0, 0);
    };

    const int nst = (klen + 31) / 32;   // 32-k steps

    loadA(a0, 0);
    for (int ts = 0; ts < nst; ts += 2) {
        loadB(ts * 32);
        if (ts + 1 < nst) loadA(a1, (ts + 1) * 32);
        compute(a0);
        if (ts + 1 < nst) {
            loadB((ts + 1) * 32);
            if (ts + 2 < nst) loadA(a0, (ts + 2) * 32);
            compute(a1);
        }
    }

    // C/D layout: col=lane&15, row=(lane>>4)*4+r  [learn_hip m89]
    const int col0 = wn * 80 + lm;
    const int rloc = wm * 32 + lq * 4;
    if (ATOMIC) {
#pragma unroll
        for (int i = 0; i < 2; ++i)
#pragma unroll
            for (int j = 0; j < 5; ++j)
#pragma unroll
                for (int r = 0; r < 4; ++r)
                    atomicAdd(&out[(size_t)(m0 + rloc + i * 16 + r) * NP + col0 + j * 16],
                              acc[i][j][r]);
    } else {
        float* P = out + (size_t)ks * Mdim * NP;
#pragma unroll
        for (int i = 0; i < 2; ++i)
#pragma unroll
            for (int j = 0; j < 5; ++j)
#pragma unroll
                for (int r = 0; r < 4; ++r)
                    P[(size_t)(m0 + rloc + i * 16 + r) * NP + col0 + j * 16] = acc[i][j][r];
    }
}

// ---------------- k3a: reduce partials + L2 normalize (partial path) --------
__global__ __launch_bounds__(320) void reduce_norm_k(const float* __restrict__ P,
                                                     float* __restrict__ out,
                                                     int split)
{
    const int b = blockIdx.x;
    const int t = threadIdx.x;
    float v = 0.f;
    for (int ks = 0; ks < split; ++ks)
        v += P[((size_t)ks * Mdim + b) * NP + t];     // coalesced per ks
    float ss = v * v;
#pragma unroll
    for (int o = 32; o > 0; o >>= 1) ss += __shfl_down(ss, o, 64);
    __shared__ float wsum[5];
    __shared__ float scale;
    if ((t & 63) == 0) wsum[t >> 6] = ss;
    __syncthreads();
    if (t == 0) {
        float s = wsum[0] + wsum[1] + wsum[2] + wsum[3] + wsum[4];
        scale = 1.0f / (sqrtf(s) + 1e-7f);
    }
    __syncthreads();
    if (t < Ndim) out[(size_t)b * Ndim + t] = v * scale;
}

// ---------------- k3b: normalize only (atomic fallback path) ----------------
__global__ __launch_bounds__(320) void normalize_k(const float* __restrict__ Cacc,
                                                   float* __restrict__ out)
{
    const int b = blockIdx.x;
    const int t = threadIdx.x;
    float v = 0.f;
    if (t < Ndim) v = Cacc[(size_t)b * NP + t];
    float ss = v * v;
#pragma unroll
    for (int o = 32; o > 0; o >>= 1) ss += __shfl_down(ss, o, 64);
    __shared__ float wsum[5];
    __shared__ float scale;
    if ((t & 63) == 0) wsum[t >> 6] = ss;
    __syncthreads();
    if (t == 0) {
        float s = wsum[0] + wsum[1] + wsum[2] + wsum[3] + wsum[4];
        scale = 1.0f / (sqrtf(s) + 1e-7f);
    }
    __syncthreads();
    if (t < Ndim) out[(size_t)b * Ndim + t] = v * scale;
}

// ---------------- launch ----------------------------------------------------
extern "C" void kernel_launch(void* const* d_in, const int* in_sizes, int n_in,
                              void* d_out, int out_size, void* d_ws, size_t ws_size,
                              hipStream_t stream)
{
    const float* labels = (const float*)d_in[0];   // 1024 x 50000
    const float* weight = (const float*)d_in[1];   // 50000 x 300
    float* out = (float*)d_out;                    // 1024 x 300

    bf16* Wt = (bf16*)d_ws;                                   // 32.0 MB at offset 0
    const size_t wtBytes  = (size_t)NP * Kdim * sizeof(bf16); // 32,000,000
    float* aux = (float*)((char*)d_ws + wtBytes);
    const size_t perSplit = (size_t)Mdim * NP * sizeof(float); // 1.31 MB

    transpose_w<<<dim3((Kdim + TK - 1) / TK), dim3(256), 0, stream>>>(weight, Wt);

    if (ws_size >= wtBytes + 32 * perSplit) {
        // partial path, SPLIT=32 (SEGLEN=1600, grid 512 = 2 blocks/CU)
        gemm_kernel<32, 1600, false><<<dim3(MT * 32), dim3(512), 0, stream>>>(labels, Wt, aux);
        reduce_norm_k<<<dim3(Mdim), dim3(320), 0, stream>>>(aux, out, 32);
    } else if (ws_size >= wtBytes + 16 * perSplit) {
        // partial path, SPLIT=16 (SEGLEN=3136, grid 256)
        gemm_kernel<16, 3136, false><<<dim3(MT * 16), dim3(512), 0, stream>>>(labels, Wt, aux);
        reduce_norm_k<<<dim3(Mdim), dim3(320), 0, stream>>>(aux, out, 16);
    } else {
        // atomic fallback (needs 33.3 MB)
        hipMemsetAsync(aux, 0, perSplit, stream);
        gemm_kernel<32, 1600, true><<<dim3(MT * 32), dim3(512), 0, stream>>>(labels, Wt, aux);
        normalize_k<<<dim3(Mdim), dim3(320), 0, stream>>>(aux, out);
    }
}